// Round 21
// baseline (189.424 us; speedup 1.0000x reference)
//
#include <hip/hip_runtime.h>
#include <math.h>

#define WWIN 9
#define BATCH 256
#define FEAT 51
#define TT 459          // WWIN*FEAT
#define EMBD 6
#define HID 306
#define G3 918
#define FFND 12
#define TOPM 80
#define MAXTASK 320
#define NPAIR 153       // HID/2
#define NPAIR2 154      // allocation pad
#define W4S 1280        // dwords per pair-row in gate-packed WHB: 320 cols x 4 dwords

__device__ __forceinline__ float leakyf(float v){ return v >= 0.f ? v : 0.01f*v; }
__device__ __forceinline__ float sigmf(float v){ return 1.f/(1.f+__expf(-v)); }

__device__ __forceinline__ unsigned fkey(float s){
    unsigned fb = __float_as_uint(s);
    unsigned m = (unsigned)((int)fb >> 31);
    return fb ^ (m | 0x80000000u);
}
__device__ __forceinline__ float fkey_inv(unsigned k){
    unsigned fb = (k & 0x80000000u) ? (k ^ 0x80000000u) : ~k;
    return __uint_as_float(fb);
}
// round-to-nearest-even f32 -> bf16 (returns low 16 bits)
__device__ __forceinline__ unsigned bfrne(float f){
    unsigned u = __float_as_uint(f);
    u += 0x7fffu + ((u >> 16) & 1u);
    return u >> 16;
}

// ---- DPP wave64 reductions ----
template<int CTRL, int RMASK>
__device__ __forceinline__ float dpp_add(float v){
    int r = __builtin_amdgcn_update_dpp(0, __float_as_int(v), CTRL, RMASK, 0xf, true);
    return v + __int_as_float(r);
}
__device__ __forceinline__ float wave_fsum(float v){
    v = dpp_add<0x111, 0xf>(v);
    v = dpp_add<0x112, 0xf>(v);
    v = dpp_add<0x114, 0xf>(v);
    v = dpp_add<0x118, 0xf>(v);
    v = dpp_add<0x142, 0xa>(v);
    v = dpp_add<0x143, 0xc>(v);
    return __int_as_float(__builtin_amdgcn_readlane(__float_as_int(v), 63));
}
template<int CTRL, int RMASK>
__device__ __forceinline__ unsigned dpp_uadd(unsigned v){
    unsigned r = (unsigned)__builtin_amdgcn_update_dpp(0, (int)v, CTRL, RMASK, 0xf, true);
    return v + r;
}
__device__ __forceinline__ unsigned wave_usum(unsigned v){
    v = dpp_uadd<0x111, 0xf>(v);
    v = dpp_uadd<0x112, 0xf>(v);
    v = dpp_uadd<0x114, 0xf>(v);
    v = dpp_uadd<0x118, 0xf>(v);
    v = dpp_uadd<0x142, 0xa>(v);
    v = dpp_uadd<0x143, 0xc>(v);
    return (unsigned)__builtin_amdgcn_readlane((int)v, 63);
}
template<int CTRL, int RMASK>
__device__ __forceinline__ unsigned dpp_min(unsigned v){
    unsigned r = (unsigned)__builtin_amdgcn_update_dpp((int)v, (int)v, CTRL, RMASK, 0xf, false);
    return v < r ? v : r;
}
__device__ __forceinline__ unsigned wave_umin(unsigned v){
    v = dpp_min<0x111, 0xf>(v);
    v = dpp_min<0x112, 0xf>(v);
    v = dpp_min<0x114, 0xf>(v);
    v = dpp_min<0x118, 0xf>(v);
    v = dpp_min<0x142, 0xa>(v);
    v = dpp_min<0x143, 0xc>(v);
    return (unsigned)__builtin_amdgcn_readlane((int)v, 63);
}

// ================= L1: embedding + QKV + task build + weight transforms =================
// TASKS pk layout: mult<<13 | f<<7 | j<<4 | repw
__global__ __launch_bounds__(512) void embed_tasks(
    const float* __restrict__ src,
    const float* __restrict__ w1w, const float* __restrict__ w1b,
    const float* __restrict__ w2w, const float* __restrict__ w2b,
    const float* __restrict__ meta,
    const float* __restrict__ Wq, const float* __restrict__ bq,
    const float* __restrict__ Wk, const float* __restrict__ bk,
    const float* __restrict__ Wv, const float* __restrict__ bv,
    const float* __restrict__ wih, const float* __restrict__ whh,
    const float* __restrict__ fcw,
    float* __restrict__ WIHT, unsigned* __restrict__ WHB, float* __restrict__ FCNT,
    float* __restrict__ X, float* __restrict__ Q,
    float* __restrict__ K, float* __restrict__ V,
    int* __restrict__ TASKS, int* __restrict__ ROWMAP, int* __restrict__ NT)
{
    __shared__ int sbuck[TT];
    int b = blockIdx.x;
    int t = threadIdx.x;

    // WIH transpose, write-coalesced (row stride G3)
    for (int idx = blockIdx.x*512 + threadIdx.x; idx < HID*G3; idx += 256*512){
        int i = idx / G3, o = idx % G3;
        WIHT[idx] = wih[(size_t)o*HID + i];
    }
    // WHH -> gate-packed bf16 pairs: WHB[p*W4S + c*4 + g] = pack(whh[g*306+c][2p], [2p+1])
    for (int idx = blockIdx.x*512 + threadIdx.x; idx < NPAIR2*W4S; idx += 256*512){
        int p = idx / W4S;
        int rem = idx - p*W4S;
        int c = rem >> 2, g = rem & 3;
        unsigned v = 0u;
        if (g < 3 && c < HID && p < NPAIR){
            const float* wr = whh + ((size_t)g*HID + c)*HID + 2*p;
            v = bfrne(wr[0]) | (bfrne(wr[1]) << 16);
        }
        WHB[idx] = v;
    }
    // FCN transpose, write-coalesced
    for (int idx = blockIdx.x*512 + threadIdx.x; idx < HID*FEAT; idx += 256*512){
        int i = idx / FEAT, f = idx % FEAT;
        FCNT[idx] = fcw[(size_t)f*HID + i];
    }

    if (t < TT){
        int w = t / FEAT, f = t % FEAT;
        float s = src[(w*BATCH + b)*FEAT + f];
        float h1[EMBD], h2[EMBD];
        #pragma unroll
        for (int i=0;i<EMBD;i++) h1[i] = leakyf(s*w1w[f*EMBD+i] + w1b[f*EMBD+i]);
        #pragma unroll
        for (int j=0;j<EMBD;j++){
            float a = 0.f;
            #pragma unroll
            for (int i=0;i<EMBD;i++) a += h1[i]*w2w[(f*EMBD+j)*EMBD+i];
            h2[j] = a + w2b[f*EMBD+j];
        }
        float z[EMBD];
        float m = -INFINITY; int jm = 0;
        #pragma unroll
        for (int j=0;j<EMBD;j++){
            z[j] = (h2[j] + 0.5f*h1[j]) * 1e+05f;
            if (z[j] > m){ m = z[j]; jm = j; }
        }
        float se = 0.f;
        #pragma unroll
        for (int j=0;j<EMBD;j++){ z[j] = expf(z[j]-m); se += z[j]; }
        float inv = 1.0f / se;
        #pragma unroll
        for (int j=0;j<EMBD;j++) z[j] *= inv;
        sbuck[t] = jm;

        float xr[EMBD];
        #pragma unroll
        for (int e=0;e<EMBD;e++){
            float a = 0.f;
            #pragma unroll
            for (int i=0;i<EMBD;i++) a += z[i]*meta[(f*EMBD+i)*EMBD+e];
            xr[e] = a * 2.449489742783178f;
        }
        float* xp = X + (b*TT + t)*EMBD;
        float* qp = Q + (b*TT + t)*EMBD;
        float* kp = K + (b*TT + t)*EMBD;
        float* vp = V + (b*TT + t)*EMBD;
        #pragma unroll
        for (int e=0;e<EMBD;e++){
            xp[e] = xr[e];
            float aq=0.f, ak=0.f, av=0.f;
            #pragma unroll
            for (int i=0;i<EMBD;i++){
                aq += xr[i]*Wq[e*EMBD+i];
                ak += xr[i]*Wk[e*EMBD+i];
                av += xr[i]*Wv[e*EMBD+i];
            }
            qp[e] = aq + bq[e];
            kp[e] = ak + bk[e];
            vp[e] = av + bv[e];
        }
    }
    __syncthreads();
    if (threadIdx.x < 64){
        int f = threadIdx.x;
        unsigned mask = 0; unsigned cnts = 0; int repw[6]; int cnt = 0;
        if (f < FEAT){
            #pragma unroll
            for (int w=0; w<WWIN; w++){
                int j = sbuck[w*FEAT + f];
                if (!((mask>>j) & 1u)){ mask |= 1u<<j; repw[j] = w; }
                cnts += 1u << (5*j);
            }
            cnt = __popc(mask);
        }
        int inc = cnt;
        #pragma unroll
        for (int off=1; off<64; off<<=1){
            int n = __shfl_up(inc, off, 64);
            if (threadIdx.x >= off) inc += n;
        }
        int offset = inc - cnt;
        if (f < FEAT){
            int rk = 0;
            #pragma unroll
            for (int j=0;j<6;j++){
                if ((mask>>j) & 1u){
                    int mult = (int)((cnts >> (5*j)) & 31u);
                    TASKS[b*MAXTASK + offset + rk] =
                        (mult<<13) | (f<<7) | (j<<4) | repw[j];
                    rk++;
                }
            }
            #pragma unroll
            for (int w=0;w<WWIN;w++){
                int j = sbuck[w*FEAT + f];
                int r = __popc(mask & ((1u<<j)-1u));
                ROWMAP[b*TT + w*FEAT + f] = offset + r;
            }
        }
        if (threadIdx.x == 63) NT[b] = inc;
    }
}

// ================= L2: attention — distinct keys + multiplicity, packed DPP descent =================
__global__ __launch_bounds__(256) void attn_topk(
    const float* __restrict__ Q, const float* __restrict__ K,
    const float* __restrict__ V, const int* __restrict__ TASKS,
    const int* __restrict__ NT, float2* __restrict__ OD)
{
    int blk = blockIdx.x;
    int b = blk / 3, h = blk % 3;
    const int base = b*TT*EMBD + 2*h;
    int wave = threadIdx.x >> 6, lane = threadIdx.x & 63;
    int nt = NT[b];

    float rkx[4], rky[4], rvx[4], rvy[4], rmf[4];
    unsigned rpm[4];
    #pragma unroll
    for (int s=0;s<4;s++){
        int tix = lane + (s<<6);
        rkx[s]=0.f; rky[s]=0.f; rvx[s]=0.f; rvy[s]=0.f; rmf[s]=0.f; rpm[s]=0u;
        if (tix < nt){
            int pk = TASKS[b*MAXTASK + tix];
            int rep_t = (pk & 15)*FEAT + ((pk >> 7) & 63);
            int mult = pk >> 13;
            rkx[s] = K[base + rep_t*EMBD];
            rky[s] = K[base + rep_t*EMBD + 1];
            rvx[s] = V[base + rep_t*EMBD];
            rvy[s] = V[base + rep_t*EMBD + 1];
            rmf[s] = (float)mult;
            rpm[s] = ((unsigned)mult << 10) | 1u;
        }
    }

    const float SC = 0.7071067811865476f;
    for (int idx = blockIdx.y*4 + wave; idx < nt; idx += 16){
        int pk = TASKS[b*MAXTASK + idx];
        int rep_t = (pk & 15)*FEAT + ((pk >> 7) & 63);
        float q0 = Q[base + rep_t*EMBD]     * SC;
        float q1 = Q[base + rep_t*EMBD + 1] * SC;

        float sv[4]; unsigned uk[4];
        #pragma unroll
        for (int s=0;s<4;s++){
            float sc = q0*rkx[s] + q1*rky[s];
            sv[s] = sc;
            uk[s] = rpm[s] ? fkey(sc) : 0u;
        }
        unsigned T = 0;
        int Dwin = nt, Dabove = 0;
        int mode = 0; unsigned Ue = 0;
        for (int bit = 31; bit >= 0; --bit){
            unsigned Tp = T | (1u<<bit);
            unsigned acc = 0;
            #pragma unroll
            for (int s=0;s<4;s++) acc += (uk[s] >= Tp) ? rpm[s] : 0u;
            acc = wave_usum(acc);
            int cw = (int)(acc >> 10);
            int dg = (int)(acc & 1023u);
            int dhi = dg - Dabove;
            if (cw >= TOPM){
                T = Tp; Dwin = dhi;
                if (cw == TOPM){ mode = 1; break; }
            } else {
                Dwin -= dhi; Dabove = dg;
            }
            if (Dwin == 1){ mode = 2; Ue = T + (1u<<bit); break; }
        }
        if (mode == 0)      Ue = T + 1u;
        else if (mode == 1) Ue = 0xFFFFFFFFu;
        unsigned mn = 0xFFFFFFFFu;
        #pragma unroll
        for (int s=0;s<4;s++){
            unsigned cand = (rpm[s] && uk[s] >= T && uk[s] < Ue) ? uk[s] : 0xFFFFFFFFu;
            mn = min(mn, cand);
        }
        unsigned kth = wave_umin(mn);
        float skth = fkey_inv(kth);
        float den=0.f, ox=0.f, oy=0.f;
        #pragma unroll
        for (int s=0;s<4;s++){
            float p = __expf(sv[s] - skth) * rmf[s];
            p = (uk[s] >= kth) ? p : 0.f;
            den += p; ox += p*rvx[s]; oy += p*rvy[s];
        }
        den = wave_fsum(den);
        ox  = wave_fsum(ox);
        oy  = wave_fsum(oy);
        if (lane == 0){
            float id = 1.0f/den;
            OD[(b*3 + h)*MAXTASK + idx] = make_float2(ox*id, oy*id);
        }
    }
}

// ================= L3: post-block fused into GI matmul (R14 config: (4,256) grid, high TLP) =================
__global__ __launch_bounds__(256) void post_gi(
    const float* __restrict__ X, const float2* __restrict__ OD,
    const int* __restrict__ ROWMAP,
    const float* __restrict__ Wo, const float* __restrict__ bo,
    const float* __restrict__ l1s, const float* __restrict__ l1b,
    const float* __restrict__ fw1, const float* __restrict__ fb1,
    const float* __restrict__ fw2, const float* __restrict__ fb2,
    const float* __restrict__ l2s, const float* __restrict__ l2b,
    const float* __restrict__ WIHT, const float* __restrict__ bih,
    float* __restrict__ GI)
{
    __shared__ float sL[8][HID];
    int gy = blockIdx.y, gx = blockIdx.x;
    for (int idx = threadIdx.x; idx < 8*FEAT; idx += 256){
        int k = idx / FEAT, ff = idx % FEAT;
        int r = gy*8 + k;
        int w = r >> 8, b = r & 255;
        int t = w*FEAT + ff;
        const float* xr = X + (b*TT + t)*EMBD;
        int rm = ROWMAP[b*TT + t];
        float orow[EMBD];
        #pragma unroll
        for (int h=0;h<3;h++){
            float2 od = OD[(b*3 + h)*MAXTASK + rm];
            orow[2*h]   = od.x;
            orow[2*h+1] = od.y;
        }
        float y[EMBD];
        #pragma unroll
        for (int e=0;e<EMBD;e++){
            float a = 0.f;
            #pragma unroll
            for (int e2=0;e2<EMBD;e2++) a += orow[e2]*Wo[e*EMBD+e2];
            y[e] = xr[e] + a + bo[e];
        }
        float mu=0.f;
        #pragma unroll
        for (int e=0;e<EMBD;e++) mu += y[e];
        mu *= (1.f/6.f);
        float var=0.f;
        #pragma unroll
        for (int e=0;e<EMBD;e++){ float d = y[e]-mu; var += d*d; }
        var *= (1.f/6.f);
        float isd = 1.0f / sqrtf(var + 1e-05f);
        float xn[EMBD];
        #pragma unroll
        for (int e=0;e<EMBD;e++) xn[e] = (y[e]-mu)*isd*l1s[e] + l1b[e];
        float hd[FFND];
        #pragma unroll
        for (int kk2=0;kk2<FFND;kk2++){
            float a = fb1[kk2];
            #pragma unroll
            for (int e=0;e<EMBD;e++) a += xn[e]*fw1[kk2*EMBD+e];
            hd[kk2] = fmaxf(a, 0.f);
        }
        float y2[EMBD];
        #pragma unroll
        for (int e=0;e<EMBD;e++){
            float a = fb2[e];
            #pragma unroll
            for (int kk2=0;kk2<FFND;kk2++) a += hd[kk2]*fw2[e*FFND+kk2];
            y2[e] = xn[e] + a;
        }
        float mu2=0.f;
        #pragma unroll
        for (int e=0;e<EMBD;e++) mu2 += y2[e];
        mu2 *= (1.f/6.f);
        float var2=0.f;
        #pragma unroll
        for (int e=0;e<EMBD;e++){ float d = y2[e]-mu2; var2 += d*d; }
        var2 *= (1.f/6.f);
        float isd2 = 1.0f / sqrtf(var2 + 1e-05f);
        #pragma unroll
        for (int e=0;e<EMBD;e++) sL[k][ff*EMBD+e] = (y2[e]-mu2)*isd2*l2s[e] + l2b[e];
    }
    __syncthreads();
    int col = gx*256 + threadIdx.x;
    if (col >= G3) return;
    float acc[8];
    #pragma unroll
    for (int k=0;k<8;k++) acc[k] = 0.f;
    for (int i=0;i<HID;i++){
        float wv = WIHT[(size_t)i*G3 + col];
        #pragma unroll
        for (int k=0;k<8;k++) acc[k] += sL[k][i]*wv;
    }
    float bb = bih[col];
    #pragma unroll
    for (int k=0;k<8;k++) GI[(size_t)(gy*8+k)*G3 + col] = acc[k] + bb;
}

// ================= L4: GRU 8 steps + FC; 256 blocks x 960 threads (3-way i-split) =================
// Gate-packed weights: one dwordx4 load per pair (3 gate dwords + pad).
#define PFR 3   // pairs per chunk; 51 = 17*3

#define LOADR(buf, c_) { \
    int p0_ = pbase + (c_)*PFR; \
    _Pragma("unroll") \
    for (int r=0;r<PFR;r++){ \
        buf[r] = *(const uint4*)(WHB + (size_t)(p0_+r)*W4S + (jc<<2)); \
    } }

#define COMPR(buf, c_) { \
    int p0_ = pbase + (c_)*PFR; \
    _Pragma("unroll") \
    for (int r=0;r<PFR;r++){ \
        float2 h2 = *(const float2*)&hL[2*(p0_+r)]; \
        unsigned pr_ = buf[r].x, pz_ = buf[r].y, pn_ = buf[r].z; \
        float wr0 = __uint_as_float(pr_ << 16), wr1 = __uint_as_float(pr_ & 0xffff0000u); \
        float wz0 = __uint_as_float(pz_ << 16), wz1 = __uint_as_float(pz_ & 0xffff0000u); \
        float wn0 = __uint_as_float(pn_ << 16), wn1 = __uint_as_float(pn_ & 0xffff0000u); \
        ar = fmaf(wr0, h2.x, fmaf(wr1, h2.y, ar)); \
        az = fmaf(wz0, h2.x, fmaf(wz1, h2.y, az)); \
        an = fmaf(wn0, h2.x, fmaf(wn1, h2.y, an)); \
    } }

__global__ __launch_bounds__(960) void gru_fcn(
    const float* __restrict__ GI, const unsigned* __restrict__ WHB,
    const float* __restrict__ bhh, const float* __restrict__ h0,
    const float* __restrict__ FCNT, const float* __restrict__ fcb,
    float* __restrict__ out)
{
    __shared__ float hL[HID + 2];
    __shared__ float pB[2*HID*3];   // partials for slices 1,2
    int b = blockIdx.x;
    int tid = threadIdx.x;
    if (tid < HID) hL[tid] = h0[(size_t)b*HID + tid];
    if (tid >= HID && tid < HID+2) hL[tid] = 0.f;
    __syncthreads();

    int s = tid / 320;          // slice 0,1,2 (wave-uniform: 320 = 5 whole waves)
    int j = tid - s*320;        // 0..319
    bool act = (j < HID);
    int jc = act ? j : 0;
    int pbase = s*51;
    float br=0.f, bz=0.f, bn=0.f;
    if (s == 0 && act){ br = bhh[j]; bz = bhh[HID+j]; bn = bhh[2*HID+j]; }

    uint4 bufA[PFR], bufB[PFR];
    LOADR(bufA, 0);             // prologue; re-issued at each step's end
    for (int step = 0; step < 8; ++step){
        float gr=0.f, gz=0.f, gn=0.f;
        if (s == 0 && act){
            const float* gi = GI + ((size_t)step*BATCH + b)*G3;
            gr = gi[j]; gz = gi[HID+j]; gn = gi[2*HID+j];
        }
        float ar = 0.f, az = 0.f, an = 0.f;
        #pragma unroll 1
        for (int p = 0; p < 8; ++p){
            LOADR(bufB, 2*p+1);
            COMPR(bufA, 2*p);
            LOADR(bufA, 2*p+2);
            COMPR(bufB, 2*p+1);
        }
        COMPR(bufA, 16);
        LOADR(bufA, 0);         // prefetch next step's chunk 0 (weights step-invariant)
        float hold = (s == 0) ? hL[jc] : 0.f;
        if (s > 0 && act){
            int base = ((s-1)*HID + j)*3;
            pB[base] = ar; pB[base+1] = az; pB[base+2] = an;
        }
        __syncthreads();   // hL reads done; partials visible
        if (s == 0 && act){
            float a2r = pB[j*3],       a2z = pB[j*3+1],       a2n = pB[j*3+2];
            float a3r = pB[(HID+j)*3], a3z = pB[(HID+j)*3+1], a3n = pB[(HID+j)*3+2];
            float rr = sigmf(gr + ar + a2r + a3r + br);
            float zz = sigmf(gz + az + a2z + a3z + bz);
            float nn = tanhf(gn + rr*(an + a2n + a3n + bn));
            hL[j] = (1.f - zz)*nn + zz*hold;
        }
        __syncthreads();
    }

    if (tid < FEAT){
        int f = tid;
        float acc = 0.f;
        #pragma unroll 6
        for (int i=0;i<HID;i++) acc += hL[i]*FCNT[i*FEAT+f];
        out[(size_t)b*FEAT + f] = sigmf(acc + fcb[f]);
    }
}

extern "C" void kernel_launch(void* const* d_in, const int* in_sizes, int n_in,
                              void* d_out, int out_size, void* d_ws, size_t ws_size,
                              hipStream_t stream)
{
    const float* src = (const float*)d_in[0];
    const float* w1w = (const float*)d_in[2];
    const float* w1b = (const float*)d_in[3];
    const float* w2w = (const float*)d_in[4];
    const float* w2b = (const float*)d_in[5];
    const float* meta= (const float*)d_in[6];
    const float* Wq = (const float*)d_in[7];  const float* bq = (const float*)d_in[8];
    const float* Wk = (const float*)d_in[9];  const float* bk = (const float*)d_in[10];
    const float* Wv = (const float*)d_in[11]; const float* bv = (const float*)d_in[12];
    const float* Wo = (const float*)d_in[13]; const float* bo = (const float*)d_in[14];
    const float* l1s= (const float*)d_in[15]; const float* l1b= (const float*)d_in[16];
    const float* fw1= (const float*)d_in[17]; const float* fb1= (const float*)d_in[18];
    const float* fw2= (const float*)d_in[19]; const float* fb2= (const float*)d_in[20];
    const float* l2s= (const float*)d_in[21]; const float* l2b= (const float*)d_in[22];
    const float* wih= (const float*)d_in[23]; const float* whh= (const float*)d_in[24];
    const float* bih= (const float*)d_in[25]; const float* bhh= (const float*)d_in[26];
    const float* h0 = (const float*)d_in[27];
    const float* fcw= (const float*)d_in[28]; const float* fcb= (const float*)d_in[29];

    float* ws = (float*)d_ws;
    float* X    = ws;                  // 705024
    float* Q    = X    + 705024;
    float* K    = Q    + 705024;
    float* V    = K    + 705024;
    float* GI   = V    + 705024;       // 1880064
    float* WIHT = GI   + 1880064;      // 280908
    unsigned* WHB = (unsigned*)(WIHT + 280908 + 4);   // 154*1280 = 197120 (16B-aligned)
    float* FCNT = (float*)(WHB + 197120);              // 15606
    float* ODf  = FCNT + 15606;        // 491520
    int*   TASKS= (int*)(ODf + 491520);    // 81920
    int*   RMAP = TASKS + 81920;           // 117504
    int*   NT   = RMAP + 117504;           // 256
    float2* OD  = (float2*)ODf;
    float* outp = (float*)d_out;

    embed_tasks<<<256, 512, 0, stream>>>(src, w1w, w1b, w2w, w2b, meta,
                                         Wq,bq,Wk,bk,Wv,bv, wih, whh, fcw,
                                         WIHT, WHB, FCNT,
                                         X,Q,K,V, TASKS, RMAP, NT);
    {
        dim3 g(768, 4);
        attn_topk<<<g, 256, 0, stream>>>(Q, K, V, TASKS, NT, OD);
    }
    {
        dim3 g(4, 256);
        post_gi<<<g, 256, 0, stream>>>(X, OD, RMAP, Wo, bo, l1s, l1b,
                                       fw1, fb1, fw2, fb2, l2s, l2b,
                                       WIHT, bih, GI);
    }
    gru_fcn<<<256, 960, 0, stream>>>(GI, WHB, bhh, h0, FCNT, fcb, outp);
}

// Round 22
// 184.632 us; speedup vs baseline: 1.0260x; 1.0260x over previous
//
#include <hip/hip_runtime.h>
#include <math.h>

#define WWIN 9
#define BATCH 256
#define FEAT 51
#define TT 459          // WWIN*FEAT
#define EMBD 6
#define HID 306
#define G3 918
#define FFND 12
#define TOPM 80
#define MAXTASK 320
#define NPAIR 153       // HID/2
#define NPAIR2 154      // allocation pad
#define WSTRIDE 920     // padded col stride of packed WHH

__device__ __forceinline__ float leakyf(float v){ return v >= 0.f ? v : 0.01f*v; }
__device__ __forceinline__ float sigmf(float v){ return 1.f/(1.f+__expf(-v)); }

__device__ __forceinline__ unsigned fkey(float s){
    unsigned fb = __float_as_uint(s);
    unsigned m = (unsigned)((int)fb >> 31);
    return fb ^ (m | 0x80000000u);
}
__device__ __forceinline__ float fkey_inv(unsigned k){
    unsigned fb = (k & 0x80000000u) ? (k ^ 0x80000000u) : ~k;
    return __uint_as_float(fb);
}
// round-to-nearest-even f32 -> bf16 (returns low 16 bits)
__device__ __forceinline__ unsigned bfrne(float f){
    unsigned u = __float_as_uint(f);
    u += 0x7fffu + ((u >> 16) & 1u);
    return u >> 16;
}

// ---- DPP wave64 reductions ----
template<int CTRL, int RMASK>
__device__ __forceinline__ float dpp_add(float v){
    int r = __builtin_amdgcn_update_dpp(0, __float_as_int(v), CTRL, RMASK, 0xf, true);
    return v + __int_as_float(r);
}
__device__ __forceinline__ float wave_fsum(float v){
    v = dpp_add<0x111, 0xf>(v);
    v = dpp_add<0x112, 0xf>(v);
    v = dpp_add<0x114, 0xf>(v);
    v = dpp_add<0x118, 0xf>(v);
    v = dpp_add<0x142, 0xa>(v);
    v = dpp_add<0x143, 0xc>(v);
    return __int_as_float(__builtin_amdgcn_readlane(__float_as_int(v), 63));
}
template<int CTRL, int RMASK>
__device__ __forceinline__ unsigned dpp_uadd(unsigned v){
    unsigned r = (unsigned)__builtin_amdgcn_update_dpp(0, (int)v, CTRL, RMASK, 0xf, true);
    return v + r;
}
__device__ __forceinline__ unsigned wave_usum(unsigned v){
    v = dpp_uadd<0x111, 0xf>(v);
    v = dpp_uadd<0x112, 0xf>(v);
    v = dpp_uadd<0x114, 0xf>(v);
    v = dpp_uadd<0x118, 0xf>(v);
    v = dpp_uadd<0x142, 0xa>(v);
    v = dpp_uadd<0x143, 0xc>(v);
    return (unsigned)__builtin_amdgcn_readlane((int)v, 63);
}
template<int CTRL, int RMASK>
__device__ __forceinline__ unsigned dpp_min(unsigned v){
    unsigned r = (unsigned)__builtin_amdgcn_update_dpp((int)v, (int)v, CTRL, RMASK, 0xf, false);
    return v < r ? v : r;
}
__device__ __forceinline__ unsigned wave_umin(unsigned v){
    v = dpp_min<0x111, 0xf>(v);
    v = dpp_min<0x112, 0xf>(v);
    v = dpp_min<0x114, 0xf>(v);
    v = dpp_min<0x118, 0xf>(v);
    v = dpp_min<0x142, 0xa>(v);
    v = dpp_min<0x143, 0xc>(v);
    return (unsigned)__builtin_amdgcn_readlane((int)v, 63);
}

// ================= L1: embedding + QKV + task build + weight transforms =================
// TASKS pk layout: mult<<13 | f<<7 | j<<4 | repw
__global__ __launch_bounds__(512) void embed_tasks(
    const float* __restrict__ src,
    const float* __restrict__ w1w, const float* __restrict__ w1b,
    const float* __restrict__ w2w, const float* __restrict__ w2b,
    const float* __restrict__ meta,
    const float* __restrict__ Wq, const float* __restrict__ bq,
    const float* __restrict__ Wk, const float* __restrict__ bk,
    const float* __restrict__ Wv, const float* __restrict__ bv,
    const float* __restrict__ wih, const float* __restrict__ whh,
    const float* __restrict__ fcw,
    float* __restrict__ WIHT, unsigned* __restrict__ WHB, float* __restrict__ FCNT,
    float* __restrict__ X, float* __restrict__ Q,
    float* __restrict__ K, float* __restrict__ V,
    int* __restrict__ TASKS, int* __restrict__ ROWMAP, int* __restrict__ NT)
{
    __shared__ int sbuck[TT];
    int b = blockIdx.x;
    int t = threadIdx.x;

    // WIH transpose, write-coalesced (row stride G3, as consumed by post_gi)
    for (int idx = blockIdx.x*512 + threadIdx.x; idx < HID*G3; idx += 256*512){
        int i = idx / G3, o = idx % G3;
        WIHT[idx] = wih[(size_t)o*HID + i];
    }
    // WHH -> packed bf16 pairs (write-coalesced: c fastest)
    for (int idx = blockIdx.x*512 + threadIdx.x; idx < NPAIR2*WSTRIDE; idx += 256*512){
        int p = idx / WSTRIDE, c = idx % WSTRIDE;
        unsigned v = 0u;
        if (c < G3 && p < NPAIR){
            unsigned lo = bfrne(whh[(size_t)c*HID + 2*p]);
            unsigned hi = bfrne(whh[(size_t)c*HID + 2*p + 1]);
            v = lo | (hi << 16);
        }
        WHB[idx] = v;
    }
    // FCN transpose, write-coalesced
    for (int idx = blockIdx.x*512 + threadIdx.x; idx < HID*FEAT; idx += 256*512){
        int i = idx / FEAT, f = idx % FEAT;
        FCNT[idx] = fcw[(size_t)f*HID + i];
    }

    if (t < TT){
        int w = t / FEAT, f = t % FEAT;
        float s = src[(w*BATCH + b)*FEAT + f];
        float h1[EMBD], h2[EMBD];
        #pragma unroll
        for (int i=0;i<EMBD;i++) h1[i] = leakyf(s*w1w[f*EMBD+i] + w1b[f*EMBD+i]);
        #pragma unroll
        for (int j=0;j<EMBD;j++){
            float a = 0.f;
            #pragma unroll
            for (int i=0;i<EMBD;i++) a += h1[i]*w2w[(f*EMBD+j)*EMBD+i];
            h2[j] = a + w2b[f*EMBD+j];
        }
        float z[EMBD];
        float m = -INFINITY; int jm = 0;
        #pragma unroll
        for (int j=0;j<EMBD;j++){
            z[j] = (h2[j] + 0.5f*h1[j]) * 1e+05f;
            if (z[j] > m){ m = z[j]; jm = j; }
        }
        float se = 0.f;
        #pragma unroll
        for (int j=0;j<EMBD;j++){ z[j] = expf(z[j]-m); se += z[j]; }
        float inv = 1.0f / se;
        #pragma unroll
        for (int j=0;j<EMBD;j++) z[j] *= inv;
        sbuck[t] = jm;

        float xr[EMBD];
        #pragma unroll
        for (int e=0;e<EMBD;e++){
            float a = 0.f;
            #pragma unroll
            for (int i=0;i<EMBD;i++) a += z[i]*meta[(f*EMBD+i)*EMBD+e];
            xr[e] = a * 2.449489742783178f;
        }
        float* xp = X + (b*TT + t)*EMBD;
        float* qp = Q + (b*TT + t)*EMBD;
        float* kp = K + (b*TT + t)*EMBD;
        float* vp = V + (b*TT + t)*EMBD;
        #pragma unroll
        for (int e=0;e<EMBD;e++){
            xp[e] = xr[e];
            float aq=0.f, ak=0.f, av=0.f;
            #pragma unroll
            for (int i=0;i<EMBD;i++){
                aq += xr[i]*Wq[e*EMBD+i];
                ak += xr[i]*Wk[e*EMBD+i];
                av += xr[i]*Wv[e*EMBD+i];
            }
            qp[e] = aq + bq[e];
            kp[e] = ak + bk[e];
            vp[e] = av + bv[e];
        }
    }
    __syncthreads();
    if (threadIdx.x < 64){
        int f = threadIdx.x;
        unsigned mask = 0; unsigned cnts = 0; int repw[6]; int cnt = 0;
        if (f < FEAT){
            #pragma unroll
            for (int w=0; w<WWIN; w++){
                int j = sbuck[w*FEAT + f];
                if (!((mask>>j) & 1u)){ mask |= 1u<<j; repw[j] = w; }
                cnts += 1u << (5*j);
            }
            cnt = __popc(mask);
        }
        int inc = cnt;
        #pragma unroll
        for (int off=1; off<64; off<<=1){
            int n = __shfl_up(inc, off, 64);
            if (threadIdx.x >= off) inc += n;
        }
        int offset = inc - cnt;
        if (f < FEAT){
            int rk = 0;
            #pragma unroll
            for (int j=0;j<6;j++){
                if ((mask>>j) & 1u){
                    int mult = (int)((cnts >> (5*j)) & 31u);
                    TASKS[b*MAXTASK + offset + rk] =
                        (mult<<13) | (f<<7) | (j<<4) | repw[j];
                    rk++;
                }
            }
            #pragma unroll
            for (int w=0;w<WWIN;w++){
                int j = sbuck[w*FEAT + f];
                int r = __popc(mask & ((1u<<j)-1u));
                ROWMAP[b*TT + w*FEAT + f] = offset + r;
            }
        }
        if (threadIdx.x == 63) NT[b] = inc;
    }
}

// ================= L2: attention — distinct keys + multiplicity, packed DPP descent =================
__global__ __launch_bounds__(256) void attn_topk(
    const float* __restrict__ Q, const float* __restrict__ K,
    const float* __restrict__ V, const int* __restrict__ TASKS,
    const int* __restrict__ NT, float2* __restrict__ OD)
{
    int blk = blockIdx.x;
    int b = blk / 3, h = blk % 3;
    const int base = b*TT*EMBD + 2*h;
    int wave = threadIdx.x >> 6, lane = threadIdx.x & 63;
    int nt = NT[b];

    float rkx[4], rky[4], rvx[4], rvy[4], rmf[4];
    unsigned rpm[4];
    #pragma unroll
    for (int s=0;s<4;s++){
        int tix = lane + (s<<6);
        rkx[s]=0.f; rky[s]=0.f; rvx[s]=0.f; rvy[s]=0.f; rmf[s]=0.f; rpm[s]=0u;
        if (tix < nt){
            int pk = TASKS[b*MAXTASK + tix];
            int rep_t = (pk & 15)*FEAT + ((pk >> 7) & 63);
            int mult = pk >> 13;
            rkx[s] = K[base + rep_t*EMBD];
            rky[s] = K[base + rep_t*EMBD + 1];
            rvx[s] = V[base + rep_t*EMBD];
            rvy[s] = V[base + rep_t*EMBD + 1];
            rmf[s] = (float)mult;
            rpm[s] = ((unsigned)mult << 10) | 1u;
        }
    }

    const float SC = 0.7071067811865476f;
    for (int idx = blockIdx.y*4 + wave; idx < nt; idx += 16){
        int pk = TASKS[b*MAXTASK + idx];
        int rep_t = (pk & 15)*FEAT + ((pk >> 7) & 63);
        float q0 = Q[base + rep_t*EMBD]     * SC;
        float q1 = Q[base + rep_t*EMBD + 1] * SC;

        float sv[4]; unsigned uk[4];
        #pragma unroll
        for (int s=0;s<4;s++){
            float sc = q0*rkx[s] + q1*rky[s];
            sv[s] = sc;
            uk[s] = rpm[s] ? fkey(sc) : 0u;
        }
        unsigned T = 0;
        int Dwin = nt, Dabove = 0;
        int mode = 0; unsigned Ue = 0;
        for (int bit = 31; bit >= 0; --bit){
            unsigned Tp = T | (1u<<bit);
            unsigned acc = 0;
            #pragma unroll
            for (int s=0;s<4;s++) acc += (uk[s] >= Tp) ? rpm[s] : 0u;
            acc = wave_usum(acc);
            int cw = (int)(acc >> 10);
            int dg = (int)(acc & 1023u);
            int dhi = dg - Dabove;
            if (cw >= TOPM){
                T = Tp; Dwin = dhi;
                if (cw == TOPM){ mode = 1; break; }
            } else {
                Dwin -= dhi; Dabove = dg;
            }
            if (Dwin == 1){ mode = 2; Ue = T + (1u<<bit); break; }
        }
        if (mode == 0)      Ue = T + 1u;
        else if (mode == 1) Ue = 0xFFFFFFFFu;
        unsigned mn = 0xFFFFFFFFu;
        #pragma unroll
        for (int s=0;s<4;s++){
            unsigned cand = (rpm[s] && uk[s] >= T && uk[s] < Ue) ? uk[s] : 0xFFFFFFFFu;
            mn = min(mn, cand);
        }
        unsigned kth = wave_umin(mn);
        float skth = fkey_inv(kth);
        float den=0.f, ox=0.f, oy=0.f;
        #pragma unroll
        for (int s=0;s<4;s++){
            float p = __expf(sv[s] - skth) * rmf[s];
            p = (uk[s] >= kth) ? p : 0.f;
            den += p; ox += p*rvx[s]; oy += p*rvy[s];
        }
        den = wave_fsum(den);
        ox  = wave_fsum(ox);
        oy  = wave_fsum(oy);
        if (lane == 0){
            float id = 1.0f/den;
            OD[(b*3 + h)*MAXTASK + idx] = make_float2(ox*id, oy*id);
        }
    }
}

// ================= L3: post-block fused into GI matmul ((4,256) grid, high TLP) =================
__global__ __launch_bounds__(256) void post_gi(
    const float* __restrict__ X, const float2* __restrict__ OD,
    const int* __restrict__ ROWMAP,
    const float* __restrict__ Wo, const float* __restrict__ bo,
    const float* __restrict__ l1s, const float* __restrict__ l1b,
    const float* __restrict__ fw1, const float* __restrict__ fb1,
    const float* __restrict__ fw2, const float* __restrict__ fb2,
    const float* __restrict__ l2s, const float* __restrict__ l2b,
    const float* __restrict__ WIHT, const float* __restrict__ bih,
    float* __restrict__ GI)
{
    __shared__ float sL[8][HID];
    int gy = blockIdx.y, gx = blockIdx.x;
    for (int idx = threadIdx.x; idx < 8*FEAT; idx += 256){
        int k = idx / FEAT, ff = idx % FEAT;
        int r = gy*8 + k;
        int w = r >> 8, b = r & 255;
        int t = w*FEAT + ff;
        const float* xr = X + (b*TT + t)*EMBD;
        int rm = ROWMAP[b*TT + t];
        float orow[EMBD];
        #pragma unroll
        for (int h=0;h<3;h++){
            float2 od = OD[(b*3 + h)*MAXTASK + rm];
            orow[2*h]   = od.x;
            orow[2*h+1] = od.y;
        }
        float y[EMBD];
        #pragma unroll
        for (int e=0;e<EMBD;e++){
            float a = 0.f;
            #pragma unroll
            for (int e2=0;e2<EMBD;e2++) a += orow[e2]*Wo[e*EMBD+e2];
            y[e] = xr[e] + a + bo[e];
        }
        float mu=0.f;
        #pragma unroll
        for (int e=0;e<EMBD;e++) mu += y[e];
        mu *= (1.f/6.f);
        float var=0.f;
        #pragma unroll
        for (int e=0;e<EMBD;e++){ float d = y[e]-mu; var += d*d; }
        var *= (1.f/6.f);
        float isd = 1.0f / sqrtf(var + 1e-05f);
        float xn[EMBD];
        #pragma unroll
        for (int e=0;e<EMBD;e++) xn[e] = (y[e]-mu)*isd*l1s[e] + l1b[e];
        float hd[FFND];
        #pragma unroll
        for (int kk2=0;kk2<FFND;kk2++){
            float a = fb1[kk2];
            #pragma unroll
            for (int e=0;e<EMBD;e++) a += xn[e]*fw1[kk2*EMBD+e];
            hd[kk2] = fmaxf(a, 0.f);
        }
        float y2[EMBD];
        #pragma unroll
        for (int e=0;e<EMBD;e++){
            float a = fb2[e];
            #pragma unroll
            for (int kk2=0;kk2<FFND;kk2++) a += hd[kk2]*fw2[e*FFND+kk2];
            y2[e] = xn[e] + a;
        }
        float mu2=0.f;
        #pragma unroll
        for (int e=0;e<EMBD;e++) mu2 += y2[e];
        mu2 *= (1.f/6.f);
        float var2=0.f;
        #pragma unroll
        for (int e=0;e<EMBD;e++){ float d = y2[e]-mu2; var2 += d*d; }
        var2 *= (1.f/6.f);
        float isd2 = 1.0f / sqrtf(var2 + 1e-05f);
        #pragma unroll
        for (int e=0;e<EMBD;e++) sL[k][ff*EMBD+e] = (y2[e]-mu2)*isd2*l2s[e] + l2b[e];
    }
    __syncthreads();
    int col = gx*256 + threadIdx.x;
    if (col >= G3) return;
    float acc[8];
    #pragma unroll
    for (int k=0;k<8;k++) acc[k] = 0.f;
    for (int i=0;i<HID;i++){
        float wv = WIHT[(size_t)i*G3 + col];
        #pragma unroll
        for (int k=0;k<8;k++) acc[k] += sL[k][i]*wv;
    }
    float bb = bih[col];
    #pragma unroll
    for (int k=0;k<8;k++) GI[(size_t)(gy*8+k)*G3 + col] = acc[k] + bb;
}

// ================= L4: GRU 8 steps + FC; 256 blocks x 960 threads (3-way i-split) =================
#define PFR 3   // pairs per chunk; 51 = 17*3

#define LOADR(buf, c_) { \
    int p0_ = pbase + (c_)*PFR; \
    _Pragma("unroll") \
    for (int r=0;r<PFR;r++){ \
        const unsigned* wp = WHB + (size_t)(p0_+r)*WSTRIDE + jc; \
        buf[3*r] = wp[0]; buf[3*r+1] = wp[HID]; buf[3*r+2] = wp[2*HID]; \
    } }

#define COMPR(buf, c_) { \
    int p0_ = pbase + (c_)*PFR; \
    _Pragma("unroll") \
    for (int r=0;r<PFR;r++){ \
        float2 h2 = *(const float2*)&hL[2*(p0_+r)]; \
        unsigned pr_ = buf[3*r], pz_ = buf[3*r+1], pn_ = buf[3*r+2]; \
        float wr0 = __uint_as_float(pr_ << 16), wr1 = __uint_as_float(pr_ & 0xffff0000u); \
        float wz0 = __uint_as_float(pz_ << 16), wz1 = __uint_as_float(pz_ & 0xffff0000u); \
        float wn0 = __uint_as_float(pn_ << 16), wn1 = __uint_as_float(pn_ & 0xffff0000u); \
        ar = fmaf(wr0, h2.x, fmaf(wr1, h2.y, ar)); \
        az = fmaf(wz0, h2.x, fmaf(wz1, h2.y, az)); \
        an = fmaf(wn0, h2.x, fmaf(wn1, h2.y, an)); \
    } }

__global__ __launch_bounds__(960) void gru_fcn(
    const float* __restrict__ GI, const unsigned* __restrict__ WHB,
    const float* __restrict__ bhh, const float* __restrict__ h0,
    const float* __restrict__ FCNT, const float* __restrict__ fcb,
    float* __restrict__ out)
{
    __shared__ float hL[HID + 2];
    __shared__ float pB[2*HID*3];   // partials for slices 1,2
    int b = blockIdx.x;
    int tid = threadIdx.x;
    if (tid < HID) hL[tid] = h0[(size_t)b*HID + tid];
    if (tid >= HID && tid < HID+2) hL[tid] = 0.f;
    __syncthreads();

    int s = tid / 320;          // slice 0,1,2 (wave-uniform: 320 = 5 whole waves)
    int j = tid - s*320;        // 0..319
    bool act = (j < HID);
    int jc = act ? j : 0;
    int pbase = s*51;
    float br=0.f, bz=0.f, bn=0.f;
    if (s == 0 && act){ br = bhh[j]; bz = bhh[HID+j]; bn = bhh[2*HID+j]; }

    unsigned bufA[3*PFR], bufB[3*PFR];
    LOADR(bufA, 0);             // prologue; re-issued at each step's end
    for (int step = 0; step < 8; ++step){
        float gr=0.f, gz=0.f, gn=0.f;
        if (s == 0 && act){
            const float* gi = GI + ((size_t)step*BATCH + b)*G3;
            gr = gi[j]; gz = gi[HID+j]; gn = gi[2*HID+j];
        }
        float ar = 0.f, az = 0.f, an = 0.f;
        #pragma unroll 1
        for (int p = 0; p < 8; ++p){
            LOADR(bufB, 2*p+1);
            COMPR(bufA, 2*p);
            LOADR(bufA, 2*p+2);
            COMPR(bufB, 2*p+1);
        }
        COMPR(bufA, 16);
        LOADR(bufA, 0);         // prefetch next step's chunk 0 (weights are step-invariant)
        float hold = (s == 0) ? hL[jc] : 0.f;
        if (s > 0 && act){
            int base = ((s-1)*HID + j)*3;
            pB[base] = ar; pB[base+1] = az; pB[base+2] = an;
        }
        __syncthreads();   // hL reads done; partials visible
        if (s == 0 && act){
            float a2r = pB[j*3],       a2z = pB[j*3+1],       a2n = pB[j*3+2];
            float a3r = pB[(HID+j)*3], a3z = pB[(HID+j)*3+1], a3n = pB[(HID+j)*3+2];
            float rr = sigmf(gr + ar + a2r + a3r + br);
            float zz = sigmf(gz + az + a2z + a3z + bz);
            float nn = tanhf(gn + rr*(an + a2n + a3n + bn));
            hL[j] = (1.f - zz)*nn + zz*hold;
        }
        __syncthreads();
    }

    if (tid < FEAT){
        int f = tid;
        float acc = 0.f;
        #pragma unroll 6
        for (int i=0;i<HID;i++) acc += hL[i]*FCNT[i*FEAT+f];
        out[(size_t)b*FEAT + f] = sigmf(acc + fcb[f]);
    }
}

extern "C" void kernel_launch(void* const* d_in, const int* in_sizes, int n_in,
                              void* d_out, int out_size, void* d_ws, size_t ws_size,
                              hipStream_t stream)
{
    const float* src = (const float*)d_in[0];
    const float* w1w = (const float*)d_in[2];
    const float* w1b = (const float*)d_in[3];
    const float* w2w = (const float*)d_in[4];
    const float* w2b = (const float*)d_in[5];
    const float* meta= (const float*)d_in[6];
    const float* Wq = (const float*)d_in[7];  const float* bq = (const float*)d_in[8];
    const float* Wk = (const float*)d_in[9];  const float* bk = (const float*)d_in[10];
    const float* Wv = (const float*)d_in[11]; const float* bv = (const float*)d_in[12];
    const float* Wo = (const float*)d_in[13]; const float* bo = (const float*)d_in[14];
    const float* l1s= (const float*)d_in[15]; const float* l1b= (const float*)d_in[16];
    const float* fw1= (const float*)d_in[17]; const float* fb1= (const float*)d_in[18];
    const float* fw2= (const float*)d_in[19]; const float* fb2= (const float*)d_in[20];
    const float* l2s= (const float*)d_in[21]; const float* l2b= (const float*)d_in[22];
    const float* wih= (const float*)d_in[23]; const float* whh= (const float*)d_in[24];
    const float* bih= (const float*)d_in[25]; const float* bhh= (const float*)d_in[26];
    const float* h0 = (const float*)d_in[27];
    const float* fcw= (const float*)d_in[28]; const float* fcb= (const float*)d_in[29];

    float* ws = (float*)d_ws;
    float* X    = ws;                  // 705024
    float* Q    = X    + 705024;
    float* K    = Q    + 705024;
    float* V    = K    + 705024;
    float* GI   = V    + 705024;       // 1880064
    float* WIHT = GI   + 1880064;      // 280908
    unsigned* WHB = (unsigned*)(WIHT + 280908 + 4);   // 154*920 = 141680
    float* FCNT = (float*)(WHB + 141680);              // 15606
    float* ODf  = FCNT + 15606;        // 491520
    int*   TASKS= (int*)(ODf + 491520);    // 81920
    int*   RMAP = TASKS + 81920;           // 117504
    int*   NT   = RMAP + 117504;           // 256
    float2* OD  = (float2*)ODf;
    float* outp = (float*)d_out;

    embed_tasks<<<256, 512, 0, stream>>>(src, w1w, w1b, w2w, w2b, meta,
                                         Wq,bq,Wk,bk,Wv,bv, wih, whh, fcw,
                                         WIHT, WHB, FCNT,
                                         X,Q,K,V, TASKS, RMAP, NT);
    {
        dim3 g(768, 4);
        attn_topk<<<g, 256, 0, stream>>>(Q, K, V, TASKS, NT, OD);
    }
    {
        dim3 g(4, 256);
        post_gi<<<g, 256, 0, stream>>>(X, OD, RMAP, Wo, bo, l1s, l1b,
                                       fw1, fb1, fw2, fb2, l2s, l2b,
                                       WIHT, bih, GI);
    }
    gru_fcn<<<256, 960, 0, stream>>>(GI, WHB, bhh, h0, FCNT, fcb, outp);
}